// Round 4
// baseline (125.812 us; speedup 1.0000x reference)
//
#include <hip/hip_runtime.h>

typedef float v2f __attribute__((ext_vector_type(2)));

#define EPS2 1e-16f

constexpr int H     = 64;
constexpr int FIN   = 7;
constexpr int BLOCK = 256;
constexpr int NCHUNK = 4;           // sources per thread (S=1024 / 256)
constexpr int NV     = NCHUNK / 2;  // v2f groups

__device__ __forceinline__ float rcpf_fast(float x) { return __builtin_amdgcn_rcpf(x); }
__device__ __forceinline__ float rsqf_fast(float x) { return __builtin_amdgcn_rsqf(x); }
__device__ __forceinline__ v2f splat(float x) { return v2f{x, x}; }
__device__ __forceinline__ v2f vfma(v2f a, v2f b, v2f c) { return __builtin_elementwise_fma(a, b, c); }

__device__ __forceinline__ float tanhf_fast(float x) {
    float cx = fminf(fmaxf(x, -15.0f), 15.0f);
    float e = __expf(2.0f * cx);
    return (e - 1.0f) * rcpf_fast(e + 1.0f);
}
__device__ __forceinline__ v2f tanhv(v2f x) {
    return v2f{tanhf_fast(x.x), tanhf_fast(x.y)};
}

// Pack per-h weight record: [W1[0..6][h], b1[h], W2[h][0..3], pad x4] = 16 floats.
// Main kernel reads these at wave-uniform addresses -> s_load_dwordx4 (SGPRs),
// removing ALL inner-loop LDS traffic.
__global__ void pack_weights(const float* __restrict__ W1,
                             const float* __restrict__ b1,
                             const float* __restrict__ W2,
                             float* __restrict__ wpk)
{
    int h = threadIdx.x;
    if (h < H) {
        float* p = wpk + h * 16;
        #pragma unroll
        for (int f = 0; f < FIN; ++f) p[f] = W1[f * H + h];
        p[7]  = b1[h];
        p[8]  = W2[h * 4 + 0];
        p[9]  = W2[h * 4 + 1];
        p[10] = W2[h * 4 + 2];
        p[11] = W2[h * 4 + 3];
        p[12] = 0.f; p[13] = 0.f; p[14] = 0.f; p[15] = 0.f;
    }
}

__global__ __launch_bounds__(BLOCK)
void bh_kernel(const float* __restrict__ refLenP,
               const float* __restrict__ srcP,   // (S,3)
               const float* __restrict__ tgtP,   // (T,3)
               const float* __restrict__ wgtP,   // (S,)
               const float* __restrict__ areaP,  // (S,)
               const float* __restrict__ srcN,   // (S,3)
               const float* __restrict__ wpk,    // (H,16) packed weights
               const float* __restrict__ b2,     // (4,)
               float* __restrict__ out,          // (T,4)
               int S)
{
    __shared__ float red[4][4];

    const int tid = threadIdx.x;
    const int t = blockIdx.x;
    const float invL = rcpf_fast(refLenP[0]);
    const float tx = tgtP[t * 3 + 0];
    const float ty = tgtP[t * 3 + 1];
    const float tz = tgtP[t * 3 + 2];

    v2f feats[NV][FIN];
    v2f ws_s[NV], wv_s[NV];
    v2f rhx[NV], rhy[NV], rhz[NV];
    v2f nhx[NV], nhy[NV], nhz[NV];

    // Phase A: geometry + features (packed pairs of chunks).
    #pragma unroll
    for (int v = 0; v < NV; ++v) {
        const int sA = tid + (2 * v) * BLOCK;
        const int sB = sA + BLOCK;
        const int cA = (sA < S) ? sA : (S - 1);
        const int cB = (sB < S) ? sB : (S - 1);
        const float wA = (sA < S) ? wgtP[cA] : 0.0f;
        const float wB = (sB < S) ? wgtP[cB] : 0.0f;

        v2f rx = v2f{(tx - srcP[cA * 3 + 0]) * invL, (tx - srcP[cB * 3 + 0]) * invL};
        v2f ry = v2f{(ty - srcP[cA * 3 + 1]) * invL, (ty - srcP[cB * 3 + 1]) * invL};
        v2f rz = v2f{(tz - srcP[cA * 3 + 2]) * invL, (tz - srcP[cB * 3 + 2]) * invL};
        v2f nx = v2f{srcN[cA * 3 + 0], srcN[cB * 3 + 0]};
        v2f ny = v2f{srcN[cA * 3 + 1], srcN[cB * 3 + 1]};
        v2f nz = v2f{srcN[cA * 3 + 2], srcN[cB * 3 + 2]};

        v2f r2 = vfma(rx, rx, vfma(ry, ry, rz * rz)) + splat(EPS2);
        v2f n2 = vfma(nx, nx, vfma(ny, ny, nz * nz)) + splat(EPS2);
        v2f inv_r = v2f{rsqf_fast(r2.x), rsqf_fast(r2.y)};
        v2f inv_n = v2f{rsqf_fast(n2.x), rsqf_fast(n2.y)};
        v2f log_r = v2f{__logf(r2.x), __logf(r2.y)} * splat(0.5f);
        v2f log_n = v2f{__logf(n2.x), __logf(n2.y)} * splat(0.5f);
        v2f cosv = vfma(rx, nx, vfma(ry, ny, rz * nz)) * inv_r * inv_n;
        v2f c2 = cosv * cosv;

        feats[v][0] = v2f{(sA < S) ? areaP[cA] : 0.0f, (sB < S) ? areaP[cB] : 0.0f};
        feats[v][1] = log_r;
        feats[v][2] = log_n;
        feats[v][3] = cosv;
        feats[v][4] = vfma(c2, splat(1.5f), splat(-0.5f));
        feats[v][5] = (c2 * splat(2.5f) - splat(1.5f)) * cosv;
        feats[v][6] = vfma(vfma(c2, splat(4.375f), splat(-3.75f)), c2, splat(0.375f));

        v2f w = v2f{wA, wB};
        ws_s[v] = w * inv_r;
        wv_s[v] = w * inv_r * inv_r;
        rhx[v] = rx * inv_r; rhy[v] = ry * inv_r; rhz[v] = rz * inv_r;
        nhx[v] = nx * inv_n; nhy[v] = ny * inv_n; nhz[v] = nz * inv_n;
    }

    // Phase B: fused MLP. Weights arrive via wave-uniform float4 loads
    // (s_load_dwordx4 -> SGPRs): no LDS, no vector-mem in the loop.
    v2f o0[NV], o1[NV], o2[NV], o3[NV];
    {
        const float bb0 = b2[0], bb1 = b2[1], bb2 = b2[2], bb3 = b2[3];
        #pragma unroll
        for (int v = 0; v < NV; ++v) {
            o0[v] = splat(bb0); o1[v] = splat(bb1);
            o2[v] = splat(bb2); o3[v] = splat(bb3);
        }
    }

    const float4* wq = reinterpret_cast<const float4*>(wpk);
    #pragma unroll 4
    for (int h = 0; h < H; ++h) {
        const float4 wa = wq[h * 4 + 0];   // W1[0..3][h]
        const float4 wb = wq[h * 4 + 1];   // W1[4..6][h], b1[h]
        const float4 w2 = wq[h * 4 + 2];   // W2[h][0..3]
        #pragma unroll
        for (int v = 0; v < NV; ++v) {
            v2f a = splat(wb.w);  // b1[h]
            a = vfma(feats[v][0], splat(wa.x), a);
            a = vfma(feats[v][1], splat(wa.y), a);
            a = vfma(feats[v][2], splat(wa.z), a);
            a = vfma(feats[v][3], splat(wa.w), a);
            a = vfma(feats[v][4], splat(wb.x), a);
            a = vfma(feats[v][5], splat(wb.y), a);
            a = vfma(feats[v][6], splat(wb.z), a);
            // silu(a) = a * rcp(1 + exp(-a))
            v2f e  = v2f{__expf(-a.x), __expf(-a.y)};
            v2f sg = v2f{rcpf_fast(1.0f + e.x), rcpf_fast(1.0f + e.y)};
            v2f hv = a * sg;
            o0[v] = vfma(hv, splat(w2.x), o0[v]);
            o1[v] = vfma(hv, splat(w2.y), o1[v]);
            o2[v] = vfma(hv, splat(w2.z), o2[v]);
            o3[v] = vfma(hv, splat(w2.w), o3[v]);
        }
    }

    // Phase C: epilogue — tanh, cross, weighted accumulation (packed).
    v2f a0 = splat(0.0f), a1 = splat(0.0f), a2 = splat(0.0f), a3 = splat(0.0f);
    #pragma unroll
    for (int v = 0; v < NV; ++v) {
        v2f t0 = tanhv(o0[v]);
        v2f t1 = tanhv(o1[v]);
        v2f t2 = tanhv(o2[v]);
        v2f t3 = tanhv(o3[v]);
        a0 = vfma(ws_s[v], t0, a0);
        v2f cxx = rhy[v] * nhz[v] - rhz[v] * nhy[v];
        v2f cxy = rhz[v] * nhx[v] - rhx[v] * nhz[v];
        v2f cxz = rhx[v] * nhy[v] - rhy[v] * nhx[v];
        v2f vx = t1 * rhx[v] + t2 * nhx[v] + t3 * cxx;
        v2f vy = t1 * rhy[v] + t2 * nhy[v] + t3 * cxy;
        v2f vz = t1 * rhz[v] + t2 * nhz[v] + t3 * cxz;
        a1 = vfma(wv_s[v], vx, a1);
        a2 = vfma(wv_s[v], vy, a2);
        a3 = vfma(wv_s[v], vz, a3);
    }
    float acc0 = a0.x + a0.y;
    float acc1 = a1.x + a1.y;
    float acc2 = a2.x + a2.y;
    float acc3 = a3.x + a3.y;

    // Phase D: block reduction (wave shuffle, then LDS across 4 waves).
    #pragma unroll
    for (int off = 32; off > 0; off >>= 1) {
        acc0 += __shfl_down(acc0, off);
        acc1 += __shfl_down(acc1, off);
        acc2 += __shfl_down(acc2, off);
        acc3 += __shfl_down(acc3, off);
    }
    const int wave = tid >> 6;
    const int lane = tid & 63;
    if (lane == 0) {
        red[wave][0] = acc0; red[wave][1] = acc1;
        red[wave][2] = acc2; red[wave][3] = acc3;
    }
    __syncthreads();
    if (tid < 4) {
        float v = red[0][tid] + red[1][tid] + red[2][tid] + red[3][tid];
        out[t * 4 + tid] = v;
    }
}

extern "C" void kernel_launch(void* const* d_in, const int* in_sizes, int n_in,
                              void* d_out, int out_size, void* d_ws, size_t ws_size,
                              hipStream_t stream) {
    const float* refLen = (const float*)d_in[0];
    const float* srcP   = (const float*)d_in[1];
    const float* tgtP   = (const float*)d_in[2];
    const float* w      = (const float*)d_in[3];
    const float* area   = (const float*)d_in[4];
    const float* srcN   = (const float*)d_in[5];
    const float* W1     = (const float*)d_in[6];
    const float* b1     = (const float*)d_in[7];
    const float* W2     = (const float*)d_in[8];
    const float* b2     = (const float*)d_in[9];
    float* out          = (float*)d_out;
    float* wpk          = (float*)d_ws;   // H*16 floats = 4 KiB, ws re-poisoned each call

    const int S = in_sizes[3];
    const int T = in_sizes[2] / 3;

    pack_weights<<<1, 64, 0, stream>>>(W1, b1, W2, wpk);
    bh_kernel<<<T, BLOCK, 0, stream>>>(refLen, srcP, tgtP, w, area, srcN,
                                       wpk, b2, out, S);
}

// Round 5
// 124.757 us; speedup vs baseline: 1.0085x; 1.0085x over previous
//
#include <hip/hip_runtime.h>

typedef float v2f __attribute__((ext_vector_type(2)));

#define EPS2 1e-16f

constexpr int H      = 64;
constexpr int BLOCK  = 256;
constexpr int NCHUNK = 4;       // source chunks per thread (S=1024 / 256)
// 0.5*ln(2): folds log_r = 0.5*ln(r2) when features carry log2(r2)
constexpr float HALF_LN2 = 0.34657359027997264f;

__device__ __forceinline__ float rcpf_fast(float x) { return __builtin_amdgcn_rcpf(x); }
__device__ __forceinline__ float rsqf_fast(float x) { return __builtin_amdgcn_rsqf(x); }
__device__ __forceinline__ v2f splat(float x) { return v2f{x, x}; }
__device__ __forceinline__ v2f vfma(v2f a, v2f b, v2f c) { return __builtin_elementwise_fma(a, b, c); }

// ws layout (floats):
//   [0, 1024)              wpk: per-h 16-float records
//   [1024, 1024+4S)        sPA: {px*invL, py*invL, pz*invL, area}
//   [1024+4S, 1024+8S)     sNB: {nhx, nhy, nhz, log2(n2)}
//   [1024+8S, 1024+9S)     sw : strengths
__global__ void prep(const float* __restrict__ refLenP,
                     const float* __restrict__ srcP,
                     const float* __restrict__ srcN,
                     const float* __restrict__ wgtP,
                     const float* __restrict__ areaP,
                     const float* __restrict__ W1,
                     const float* __restrict__ b1,
                     const float* __restrict__ W2,
                     float* __restrict__ ws, int S)
{
    const int nSrcBlk = (S + BLOCK - 1) / BLOCK;
    const int bid = blockIdx.x;
    if (bid < nSrcBlk) {
        const int s = bid * BLOCK + threadIdx.x;
        if (s < S) {
            const float invL = rcpf_fast(refLenP[0]);
            float px = srcP[s * 3 + 0] * invL;
            float py = srcP[s * 3 + 1] * invL;
            float pz = srcP[s * 3 + 2] * invL;
            float nx = srcN[s * 3 + 0];
            float ny = srcN[s * 3 + 1];
            float nz = srcN[s * 3 + 2];
            float n2 = fmaf(nx, nx, fmaf(ny, ny, nz * nz)) + EPS2;
            float inv_n = rsqf_fast(n2);
            float l2n = __log2f(n2);
            float4* sPA = (float4*)(ws + 1024);
            float4* sNB = (float4*)(ws + 1024 + 4 * S);
            float*  sw  = ws + 1024 + 8 * S;
            sPA[s] = make_float4(px, py, pz, areaP[s]);
            sNB[s] = make_float4(nx * inv_n, ny * inv_n, nz * inv_n, l2n);
            sw[s]  = wgtP[s];
        }
    } else {
        const int h = threadIdx.x;
        if (h < H) {
            float* p = ws + h * 16;
            p[0] = W1[0 * H + h];              // area coeff
            p[1] = W1[1 * H + h] * HALF_LN2;   // * log2(r2)
            p[2] = W1[2 * H + h] * HALF_LN2;   // * log2(n2)
            p[3] = W1[3 * H + h];              // P1..P4
            p[4] = W1[4 * H + h];
            p[5] = W1[5 * H + h];
            p[6] = W1[6 * H + h];
            p[7] = b1[h];
            p[8]  = 2.0f * W2[h * 4 + 0];      // tanh 2x folded
            p[9]  = 2.0f * W2[h * 4 + 1];
            p[10] = 2.0f * W2[h * 4 + 2];
            p[11] = 2.0f * W2[h * 4 + 3];
            p[12] = 0.f; p[13] = 0.f; p[14] = 0.f; p[15] = 0.f;
        }
    }
}

__global__ __launch_bounds__(BLOCK)
void bh_kernel(const float* __restrict__ refLenP,
               const float* __restrict__ tgtP,
               const float* __restrict__ b2,
               const float* __restrict__ ws,
               float* __restrict__ out,
               int S, int T)
{
    __shared__ float red[4][8];

    const int tid = threadIdx.x;
    const int t0 = blockIdx.x * 2;
    const int t1 = t0 + 1;
    const bool has1 = (t1 < T);
    const int t1c = has1 ? t1 : t0;

    const float invL = rcpf_fast(refLenP[0]);
    const v2f txv = v2f{tgtP[t0 * 3 + 0] * invL, tgtP[t1c * 3 + 0] * invL};
    const v2f tyv = v2f{tgtP[t0 * 3 + 1] * invL, tgtP[t1c * 3 + 1] * invL};
    const v2f tzv = v2f{tgtP[t0 * 3 + 2] * invL, tgtP[t1c * 3 + 2] * invL};

    const float4* __restrict__ sPA = (const float4*)(ws + 1024);
    const float4* __restrict__ sNB = (const float4*)(ws + 1024 + 4 * S);
    const float*  __restrict__ sw  = ws + 1024 + 8 * S;
    const float4* __restrict__ wq  = (const float4*)ws;

    // ---- Phase A: pair features (v2f packs the two targets) ----
    v2f f1[NCHUNK], f3[NCHUNK], f4[NCHUNK], f5[NCHUNK], f6[NCHUNK];
    float fa[NCHUNK], f2s[NCHUNK];
    #pragma unroll
    for (int c = 0; c < NCHUNK; ++c) {
        const int s = tid + c * BLOCK;
        const int sc = (s < S) ? s : (S - 1);
        const float4 pa = sPA[sc];
        const float4 nb = sNB[sc];
        v2f rx = txv - splat(pa.x);
        v2f ry = tyv - splat(pa.y);
        v2f rz = tzv - splat(pa.z);
        v2f r2 = vfma(rx, rx, vfma(ry, ry, vfma(rz, rz, splat(EPS2))));
        v2f ir = v2f{rsqf_fast(r2.x), rsqf_fast(r2.y)};
        f1[c] = v2f{__log2f(r2.x), __log2f(r2.y)};
        v2f cosv = vfma(rx, splat(nb.x), vfma(ry, splat(nb.y), rz * splat(nb.z))) * ir;
        v2f c2 = cosv * cosv;
        fa[c]  = pa.w;   // area (target-independent)
        f2s[c] = nb.w;   // log2(n2)
        f3[c] = cosv;
        f4[c] = vfma(c2, splat(1.5f), splat(-0.5f));
        f5[c] = (c2 * splat(2.5f) - splat(1.5f)) * cosv;
        f6[c] = vfma(vfma(c2, splat(4.375f), splat(-3.75f)), c2, splat(0.375f));
    }

    // ---- Phase B: fused MLP ----
    v2f o0[NCHUNK], o1[NCHUNK], o2[NCHUNK], o3[NCHUNK];
    {
        const float b20 = 2.0f * b2[0], b21 = 2.0f * b2[1];
        const float b22 = 2.0f * b2[2], b23 = 2.0f * b2[3];
        #pragma unroll
        for (int c = 0; c < NCHUNK; ++c) {
            o0[c] = splat(b20); o1[c] = splat(b21);
            o2[c] = splat(b22); o3[c] = splat(b23);
        }
    }

    #pragma unroll 2
    for (int h = 0; h < H; ++h) {
        const float4 wa = wq[h * 4 + 0];   // W1[0..3] coeffs
        const float4 wb = wq[h * 4 + 1];   // W1[4..6], b1
        const float4 w2 = wq[h * 4 + 2];   // 2*W2 row
        #pragma unroll
        for (int c = 0; c < NCHUNK; ++c) {
            // target-shared part as scalar FMAs (2cyc vs 4cyc pk)
            float abase = fmaf(fa[c], wa.x, fmaf(f2s[c], wa.z, wb.w));
            v2f a = vfma(f1[c], splat(wa.y), splat(abase));
            a = vfma(f3[c], splat(wa.w), a);
            a = vfma(f4[c], splat(wb.x), a);
            a = vfma(f5[c], splat(wb.y), a);
            a = vfma(f6[c], splat(wb.z), a);
            // silu(a) = a * rcp(1 + exp(-a))
            v2f e  = v2f{__expf(-a.x), __expf(-a.y)};
            v2f sg = v2f{rcpf_fast(1.0f + e.x), rcpf_fast(1.0f + e.y)};
            v2f hv = a * sg;
            o0[c] = vfma(hv, splat(w2.x), o0[c]);
            o1[c] = vfma(hv, splat(w2.y), o1[c]);
            o2[c] = vfma(hv, splat(w2.z), o2[c]);
            o3[c] = vfma(hv, splat(w2.w), o3[c]);
        }
    }

    // ---- Phase C: epilogue (geometry recomputed from L1-hot loads) ----
    v2f a0 = splat(0.f), a1 = splat(0.f), a2 = splat(0.f), a3 = splat(0.f);
    #pragma unroll
    for (int c = 0; c < NCHUNK; ++c) {
        const int s = tid + c * BLOCK;
        const int sc = (s < S) ? s : (S - 1);
        const float4 pa = sPA[sc];
        const float4 nb = sNB[sc];
        const float wgt = (s < S) ? sw[sc] : 0.0f;
        v2f rx = txv - splat(pa.x);
        v2f ry = tyv - splat(pa.y);
        v2f rz = tzv - splat(pa.z);
        v2f r2 = vfma(rx, rx, vfma(ry, ry, vfma(rz, rz, splat(EPS2))));
        v2f ir = v2f{rsqf_fast(r2.x), rsqf_fast(r2.y)};
        v2f wsv = splat(wgt) * ir;      // w * inv_r
        v2f wvv = wsv * ir;             // w * inv_r^2

        // tanh via folded 2x: t = (e-1)/(e+1), e = exp(2*o_true) (o regs already 2x)
        v2f tt[4];
        v2f oo[4] = {o0[c], o1[c], o2[c], o3[c]};
        #pragma unroll
        for (int k = 0; k < 4; ++k) {
            v2f m = __builtin_elementwise_min(__builtin_elementwise_max(oo[k], splat(-80.f)), splat(80.f));
            v2f e = v2f{__expf(m.x), __expf(m.y)};
            v2f num = e - splat(1.0f);
            v2f den = v2f{rcpf_fast(e.x + 1.0f), rcpf_fast(e.y + 1.0f)};
            tt[k] = num * den;
        }

        a0 = vfma(wsv, tt[0], a0);
        v2f rhx = rx * ir, rhy = ry * ir, rhz = rz * ir;
        v2f cxx = rhy * splat(nb.z) - rhz * splat(nb.y);
        v2f cxy = rhz * splat(nb.x) - rhx * splat(nb.z);
        v2f cxz = rhx * splat(nb.y) - rhy * splat(nb.x);
        v2f vx = tt[1] * rhx + tt[2] * splat(nb.x) + tt[3] * cxx;
        v2f vy = tt[1] * rhy + tt[2] * splat(nb.y) + tt[3] * cxy;
        v2f vz = tt[1] * rhz + tt[2] * splat(nb.z) + tt[3] * cxz;
        a1 = vfma(wvv, vx, a1);
        a2 = vfma(wvv, vy, a2);
        a3 = vfma(wvv, vz, a3);
    }

    // ---- Phase D: reduction (wave shuffle on 8 floats, then LDS) ----
    float r8[8] = {a0.x, a1.x, a2.x, a3.x, a0.y, a1.y, a2.y, a3.y};
    #pragma unroll
    for (int off = 32; off > 0; off >>= 1) {
        #pragma unroll
        for (int k = 0; k < 8; ++k) r8[k] += __shfl_down(r8[k], off);
    }
    const int wave = tid >> 6;
    const int lane = tid & 63;
    if (lane == 0) {
        #pragma unroll
        for (int k = 0; k < 8; ++k) red[wave][k] = r8[k];
    }
    __syncthreads();
    if (tid < 8) {
        float v = red[0][tid] + red[1][tid] + red[2][tid] + red[3][tid];
        if (tid < 4) out[t0 * 4 + tid] = v;
        else if (has1) out[t1 * 4 + (tid - 4)] = v;
    }
}

extern "C" void kernel_launch(void* const* d_in, const int* in_sizes, int n_in,
                              void* d_out, int out_size, void* d_ws, size_t ws_size,
                              hipStream_t stream) {
    const float* refLen = (const float*)d_in[0];
    const float* srcP   = (const float*)d_in[1];
    const float* tgtP   = (const float*)d_in[2];
    const float* w      = (const float*)d_in[3];
    const float* area   = (const float*)d_in[4];
    const float* srcN   = (const float*)d_in[5];
    const float* W1     = (const float*)d_in[6];
    const float* b1     = (const float*)d_in[7];
    const float* W2     = (const float*)d_in[8];
    const float* b2     = (const float*)d_in[9];
    float* out          = (float*)d_out;
    float* ws           = (float*)d_ws;

    const int S = in_sizes[3];
    const int T = in_sizes[2] / 3;
    const int nSrcBlk = (S + BLOCK - 1) / BLOCK;
    const int nTgtBlk = (T + 1) / 2;

    prep<<<nSrcBlk + 1, BLOCK, 0, stream>>>(refLen, srcP, srcN, w, area, W1, b1, W2, ws, S);
    bh_kernel<<<nTgtBlk, BLOCK, 0, stream>>>(refLen, tgtP, b2, ws, out, S, T);
}

// Round 6
// 120.495 us; speedup vs baseline: 1.0441x; 1.0354x over previous
//
#include <hip/hip_runtime.h>

typedef float v2f __attribute__((ext_vector_type(2)));

#define EPS2 1e-16f

constexpr int H      = 64;
constexpr int PBLOCK = 256;     // prep block size
constexpr int BLOCK  = 512;     // main kernel: 8 waves -> 8 waves/SIMD at 4 blk/CU
constexpr int NCHUNK = 2;       // source chunks per thread (S=1024 / 512)
constexpr float LOG2E = 1.4426950408889634f;

__device__ __forceinline__ float rcpf_fast(float x) { return __builtin_amdgcn_rcpf(x); }
__device__ __forceinline__ float rsqf_fast(float x) { return __builtin_amdgcn_rsqf(x); }
__device__ __forceinline__ float exp2_fast(float x) { return __builtin_amdgcn_exp2f(x); }
__device__ __forceinline__ v2f splat(float x) { return v2f{x, x}; }
__device__ __forceinline__ v2f vfma(v2f a, v2f b, v2f c) { return __builtin_elementwise_fma(a, b, c); }

// ws layout (floats):
//   [0, 1024)              wpk: per-h 16-float records (pre-folded scales)
//   [1024, 1024+4S)        sPA: {px*invL, py*invL, pz*invL, area}
//   [1024+4S, 1024+8S)     sNB: {nhx, nhy, nhz, log2(n2)}
//   [1024+8S, 1024+9S)     sw : strengths
//
// Weight folding (exact algebra, verified both directions):
//   a_reg   = -log2e * a_true          (so sigmoid e = exp2(a_reg) = e^{-a_true})
//   p[1],p[2] = -0.5*W1 (log2-features absorb the ln2)
//   hv_reg  = a_reg * sg;  hv_true*W2 == hv_reg * (-2*W2) * log2e ... folded so that
//   o_reg   = 2*log2e * o_true  ->  tanh = (E-1)/(E+1), E = exp2(o_reg)
__global__ void prep(const float* __restrict__ refLenP,
                     const float* __restrict__ srcP,
                     const float* __restrict__ srcN,
                     const float* __restrict__ wgtP,
                     const float* __restrict__ areaP,
                     const float* __restrict__ W1,
                     const float* __restrict__ b1,
                     const float* __restrict__ W2,
                     float* __restrict__ ws, int S)
{
    const int nSrcBlk = (S + PBLOCK - 1) / PBLOCK;
    const int bid = blockIdx.x;
    if (bid < nSrcBlk) {
        const int s = bid * PBLOCK + threadIdx.x;
        if (s < S) {
            const float invL = rcpf_fast(refLenP[0]);
            float px = srcP[s * 3 + 0] * invL;
            float py = srcP[s * 3 + 1] * invL;
            float pz = srcP[s * 3 + 2] * invL;
            float nx = srcN[s * 3 + 0];
            float ny = srcN[s * 3 + 1];
            float nz = srcN[s * 3 + 2];
            float n2 = fmaf(nx, nx, fmaf(ny, ny, nz * nz)) + EPS2;
            float inv_n = rsqf_fast(n2);
            float l2n = __log2f(n2);
            float4* sPA = (float4*)(ws + 1024);
            float4* sNB = (float4*)(ws + 1024 + 4 * S);
            float*  sw  = ws + 1024 + 8 * S;
            sPA[s] = make_float4(px, py, pz, areaP[s]);
            sNB[s] = make_float4(nx * inv_n, ny * inv_n, nz * inv_n, l2n);
            sw[s]  = wgtP[s];
        }
    } else {
        const int h = threadIdx.x;
        if (h < H) {
            float* p = ws + h * 16;
            p[0] = -LOG2E * W1[0 * H + h];     // area
            p[1] = -0.5f  * W1[1 * H + h];     // * log2(r2)
            p[2] = -0.5f  * W1[2 * H + h];     // * log2(n2)
            p[3] = -LOG2E * W1[3 * H + h];     // P1..P4
            p[4] = -LOG2E * W1[4 * H + h];
            p[5] = -LOG2E * W1[5 * H + h];
            p[6] = -LOG2E * W1[6 * H + h];
            p[7] = -LOG2E * b1[h];
            p[8]  = -2.0f * W2[h * 4 + 0];
            p[9]  = -2.0f * W2[h * 4 + 1];
            p[10] = -2.0f * W2[h * 4 + 2];
            p[11] = -2.0f * W2[h * 4 + 3];
            p[12] = 0.f; p[13] = 0.f; p[14] = 0.f; p[15] = 0.f;
        }
    }
}

__global__ __launch_bounds__(BLOCK, 8)
void bh_kernel(const float* __restrict__ refLenP,
               const float* __restrict__ tgtP,
               const float* __restrict__ b2,
               const float* __restrict__ ws,
               float* __restrict__ out,
               int S, int T)
{
    __shared__ float red[8][8];

    const int tid = threadIdx.x;
    const int t0 = blockIdx.x * 2;
    const int t1 = t0 + 1;
    const bool has1 = (t1 < T);
    const int t1c = has1 ? t1 : t0;

    const float invL = rcpf_fast(refLenP[0]);
    const v2f txv = v2f{tgtP[t0 * 3 + 0] * invL, tgtP[t1c * 3 + 0] * invL};
    const v2f tyv = v2f{tgtP[t0 * 3 + 1] * invL, tgtP[t1c * 3 + 1] * invL};
    const v2f tzv = v2f{tgtP[t0 * 3 + 2] * invL, tgtP[t1c * 3 + 2] * invL};

    const float4* __restrict__ sPA = (const float4*)(ws + 1024);
    const float4* __restrict__ sNB = (const float4*)(ws + 1024 + 4 * S);
    const float*  __restrict__ sw  = ws + 1024 + 8 * S;
    const float4* __restrict__ wq  = (const float4*)ws;

    // ---- Phase A: pair features (v2f packs the two targets) ----
    v2f f1[NCHUNK], f3[NCHUNK], f4[NCHUNK], f5[NCHUNK], f6[NCHUNK];
    float fa[NCHUNK], f2s[NCHUNK];
    #pragma unroll
    for (int c = 0; c < NCHUNK; ++c) {
        const int s = tid + c * BLOCK;
        const int sc = (s < S) ? s : (S - 1);
        const float4 pa = sPA[sc];
        const float4 nb = sNB[sc];
        v2f rx = txv - splat(pa.x);
        v2f ry = tyv - splat(pa.y);
        v2f rz = tzv - splat(pa.z);
        v2f r2 = vfma(rx, rx, vfma(ry, ry, vfma(rz, rz, splat(EPS2))));
        v2f ir = v2f{rsqf_fast(r2.x), rsqf_fast(r2.y)};
        f1[c] = v2f{__log2f(r2.x), __log2f(r2.y)};
        v2f cosv = vfma(rx, splat(nb.x), vfma(ry, splat(nb.y), rz * splat(nb.z))) * ir;
        v2f c2 = cosv * cosv;
        fa[c]  = pa.w;   // area (target-independent)
        f2s[c] = nb.w;   // log2(n2)
        f3[c] = cosv;
        f4[c] = vfma(c2, splat(1.5f), splat(-0.5f));
        f5[c] = (c2 * splat(2.5f) - splat(1.5f)) * cosv;
        f6[c] = vfma(vfma(c2, splat(4.375f), splat(-3.75f)), c2, splat(0.375f));
    }

    // ---- Phase B: fused MLP (folded scales; raw v_exp_f32, no muls) ----
    v2f o0[NCHUNK], o1[NCHUNK], o2[NCHUNK], o3[NCHUNK];
    {
        const float s2 = 2.0f * LOG2E;
        const float b20 = s2 * b2[0], b21 = s2 * b2[1];
        const float b22 = s2 * b2[2], b23 = s2 * b2[3];
        #pragma unroll
        for (int c = 0; c < NCHUNK; ++c) {
            o0[c] = splat(b20); o1[c] = splat(b21);
            o2[c] = splat(b22); o3[c] = splat(b23);
        }
    }

    #pragma unroll 4
    for (int h = 0; h < H; ++h) {
        const float4 wa = wq[h * 4 + 0];
        const float4 wb = wq[h * 4 + 1];
        const float4 w2 = wq[h * 4 + 2];
        #pragma unroll
        for (int c = 0; c < NCHUNK; ++c) {
            // target-shared part as scalar FMAs
            float abase = fmaf(fa[c], wa.x, fmaf(f2s[c], wa.z, wb.w));
            v2f a = vfma(f1[c], splat(wa.y), splat(abase));
            a = vfma(f3[c], splat(wa.w), a);
            a = vfma(f4[c], splat(wb.x), a);
            a = vfma(f5[c], splat(wb.y), a);
            a = vfma(f6[c], splat(wb.z), a);
            // e = 2^a = exp(-a_true); sg = sigmoid(a_true)
            v2f e  = v2f{exp2_fast(a.x), exp2_fast(a.y)};
            v2f sg = v2f{rcpf_fast(1.0f + e.x), rcpf_fast(1.0f + e.y)};
            v2f hv = a * sg;
            o0[c] = vfma(hv, splat(w2.x), o0[c]);
            o1[c] = vfma(hv, splat(w2.y), o1[c]);
            o2[c] = vfma(hv, splat(w2.z), o2[c]);
            o3[c] = vfma(hv, splat(w2.w), o3[c]);
        }
    }

    // ---- Phase C: epilogue (geometry recomputed from L1-hot loads) ----
    v2f a0 = splat(0.f), a1 = splat(0.f), a2 = splat(0.f), a3 = splat(0.f);
    #pragma unroll
    for (int c = 0; c < NCHUNK; ++c) {
        const int s = tid + c * BLOCK;
        const int sc = (s < S) ? s : (S - 1);
        const float4 pa = sPA[sc];
        const float4 nb = sNB[sc];
        const float wgt = (s < S) ? sw[sc] : 0.0f;
        v2f rx = txv - splat(pa.x);
        v2f ry = tyv - splat(pa.y);
        v2f rz = tzv - splat(pa.z);
        v2f r2 = vfma(rx, rx, vfma(ry, ry, vfma(rz, rz, splat(EPS2))));
        v2f ir = v2f{rsqf_fast(r2.x), rsqf_fast(r2.y)};
        v2f wsv = splat(wgt) * ir;      // w * inv_r
        v2f wvv = wsv * ir;             // w * inv_r^2

        // tanh: t = (E-1)/(E+1), E = 2^{o_reg} = e^{2*o_true}
        v2f tt[4];
        v2f oo[4] = {o0[c], o1[c], o2[c], o3[c]};
        #pragma unroll
        for (int k = 0; k < 4; ++k) {
            v2f m = __builtin_elementwise_min(__builtin_elementwise_max(oo[k], splat(-126.f)), splat(126.f));
            v2f E = v2f{exp2_fast(m.x), exp2_fast(m.y)};
            v2f num = E - splat(1.0f);
            v2f den = v2f{rcpf_fast(E.x + 1.0f), rcpf_fast(E.y + 1.0f)};
            tt[k] = num * den;
        }

        a0 = vfma(wsv, tt[0], a0);
        v2f rhx = rx * ir, rhy = ry * ir, rhz = rz * ir;
        v2f cxx = rhy * splat(nb.z) - rhz * splat(nb.y);
        v2f cxy = rhz * splat(nb.x) - rhx * splat(nb.z);
        v2f cxz = rhx * splat(nb.y) - rhy * splat(nb.x);
        v2f vx = tt[1] * rhx + tt[2] * splat(nb.x) + tt[3] * cxx;
        v2f vy = tt[1] * rhy + tt[2] * splat(nb.y) + tt[3] * cxy;
        v2f vz = tt[1] * rhz + tt[2] * splat(nb.z) + tt[3] * cxz;
        a1 = vfma(wvv, vx, a1);
        a2 = vfma(wvv, vy, a2);
        a3 = vfma(wvv, vz, a3);
    }

    // ---- Phase D: reduction (wave shuffle on 8 floats, then LDS, 8 waves) ----
    float r8[8] = {a0.x, a1.x, a2.x, a3.x, a0.y, a1.y, a2.y, a3.y};
    #pragma unroll
    for (int off = 32; off > 0; off >>= 1) {
        #pragma unroll
        for (int k = 0; k < 8; ++k) r8[k] += __shfl_down(r8[k], off);
    }
    const int wave = tid >> 6;
    const int lane = tid & 63;
    if (lane == 0) {
        #pragma unroll
        for (int k = 0; k < 8; ++k) red[wave][k] = r8[k];
    }
    __syncthreads();
    if (tid < 8) {
        float v = 0.0f;
        #pragma unroll
        for (int w = 0; w < 8; ++w) v += red[w][tid];
        if (tid < 4) out[t0 * 4 + tid] = v;
        else if (has1) out[t1 * 4 + (tid - 4)] = v;
    }
}

extern "C" void kernel_launch(void* const* d_in, const int* in_sizes, int n_in,
                              void* d_out, int out_size, void* d_ws, size_t ws_size,
                              hipStream_t stream) {
    const float* refLen = (const float*)d_in[0];
    const float* srcP   = (const float*)d_in[1];
    const float* tgtP   = (const float*)d_in[2];
    const float* w      = (const float*)d_in[3];
    const float* area   = (const float*)d_in[4];
    const float* srcN   = (const float*)d_in[5];
    const float* W1     = (const float*)d_in[6];
    const float* b1     = (const float*)d_in[7];
    const float* W2     = (const float*)d_in[8];
    const float* b2     = (const float*)d_in[9];
    float* out          = (float*)d_out;
    float* ws           = (float*)d_ws;

    const int S = in_sizes[3];
    const int T = in_sizes[2] / 3;
    const int nSrcBlk = (S + PBLOCK - 1) / PBLOCK;
    const int nTgtBlk = (T + 1) / 2;

    prep<<<nSrcBlk + 1, PBLOCK, 0, stream>>>(refLen, srcP, srcN, w, area, W1, b1, W2, ws, S);
    bh_kernel<<<nTgtBlk, BLOCK, 0, stream>>>(refLen, tgtP, b2, ws, out, S, T);
}